// Round 1
// 197.533 us; speedup vs baseline: 1.0246x; 1.0246x over previous
//
#include <hip/hip_runtime.h>
#include <hip/hip_bf16.h>
#include <stdint.h>

// Problem constants
#define EXP 8
#define DIM 1024
#define SEQL 512
#define BATCH 8
#define OUT_FINAL_N (BATCH * SEQL * DIM)   // 4194304
#define OFF_AUX    4194304
#define OFF_MASK   4194305
#define OFF_LOGITS 4194369

typedef __bf16 bf16_t;
typedef bf16_t bf16x8 __attribute__((ext_vector_type(8)));
typedef bf16_t bf16x4 __attribute__((ext_vector_type(4)));
typedef float  f32x4  __attribute__((ext_vector_type(4)));

typedef __attribute__((address_space(1))) void* as1p;
typedef __attribute__((address_space(3))) void* as3p;

__device__ __forceinline__ void glds16(const void* g, void* l) {
  // async global->LDS, 16B per lane; LDS dest = wave-uniform base + lane*16
  __builtin_amdgcn_global_load_lds((as1p)(void*)g, (as3p)l, 16, 0, 0);
}

// ---------------------------------------------------------------------------
// prep_kernel: fused { weight transpose-cast | x cast | router }.
// grid.x = 2048 (transpose 128k x 64n tiles) + 512 (x cast) + 1 (router).
// Transpose: fp32 LDS tile [n][k] (64 x 129, odd stride -> free write banks),
// written transposed (4 scalar ds_write per float4), read k-contiguous,
// cast at read, 256B-contiguous bf16x8 stores.
// ---------------------------------------------------------------------------
__global__ __launch_bounds__(256) void prep_kernel(
    const float* __restrict__ x, const float* __restrict__ dec,
    const float* __restrict__ rw, const float* __restrict__ rb,
    const float* __restrict__ w1, const float* __restrict__ w2,
    bf16_t* __restrict__ xb, bf16_t* __restrict__ w1t, bf16_t* __restrict__ w2t,
    float* __restrict__ out_aux, float* __restrict__ out_mask,
    float* __restrict__ out_logits, int* __restrict__ idx_ws,
    float* __restrict__ w_ws) {
  __shared__ float tile[64][129];    // 33024 B, [n][k] transposed tile
  __shared__ float part[256];
  __shared__ float lg64[64];
  __shared__ float probs[64];
  __shared__ float msk[64];
  const int bid = blockIdx.x;
  const int t = threadIdx.x;

  if (bid < 2048) {
    // ---- transpose-cast: matrix z, tile = 128 k-rows x 64 n-cols ----
    const int z = bid >> 7;              // 16 matrices
    const int rem = bid & 127;
    const int k0 = (rem >> 4) * 128;     // 8 k-tiles
    const int n0 = (rem & 15) * 64;      // 16 n-tiles
    const float* src = (z < 8) ? (w1 + (size_t)z * DIM * DIM)
                               : (w2 + (size_t)(z - 8) * DIM * DIM);
    bf16_t* dst = (z < 8) ? (w1t + (size_t)z * DIM * DIM)
                          : (w2t + (size_t)(z - 8) * DIM * DIM);
    const int rr = t >> 4, c4 = t & 15;
    // batched loads: 8 float4 in flight (128 B/thread)
    float4 v[8];
#pragma unroll
    for (int i = 0; i < 8; ++i)
      v[i] = *(const float4*)(src + (size_t)(k0 + rr + 16 * i) * DIM + n0 + c4 * 4);
    // scatter transposed into LDS: tile[n][k]
#pragma unroll
    for (int i = 0; i < 8; ++i) {
      const int k = rr + 16 * i;
      tile[c4 * 4 + 0][k] = v[i].x;
      tile[c4 * 4 + 1][k] = v[i].y;
      tile[c4 * 4 + 2][k] = v[i].z;
      tile[c4 * 4 + 3][k] = v[i].w;
    }
    __syncthreads();
    // read k-contiguous, cast, 16B stores (wave covers 4 x 256B rows/instr)
#pragma unroll
    for (int ii = 0; ii < 4; ++ii) {
      const int n = (t >> 4) + 16 * ii;
      const int c = t & 15;
      bf16x8 o;
#pragma unroll
      for (int wd = 0; wd < 8; ++wd) o[wd] = (bf16_t)tile[n][c * 8 + wd];
      *(bf16x8*)(dst + (size_t)(n0 + n) * DIM + k0 + c * 8) = o;
    }
  } else if (bid < 2048 + 512) {
    // ---- cast x: 1M float4s over 512 blocks, 8 per thread, batched ----
    const int i0 = (bid - 2048) * 2048 + t;
    float4 v[8];
#pragma unroll
    for (int i = 0; i < 8; ++i) v[i] = ((const float4*)x)[i0 + i * 256];
#pragma unroll
    for (int i = 0; i < 8; ++i) {
      bf16x4 o;
      o[0] = (bf16_t)v[i].x; o[1] = (bf16_t)v[i].y;
      o[2] = (bf16_t)v[i].z; o[3] = (bf16_t)v[i].w;
      ((bf16x4*)xb)[i0 + i * 256] = o;
    }
  } else {
    // ---- router ----
    const int p = t >> 2, seg = t & 3;
    const int b = p >> 3, e = p & 7;
    const float4* dv = (const float4*)(dec + b * DIM + seg * 256);
    const float4* wv = (const float4*)(rw + e * DIM + seg * 256);
    float s = 0.f;
#pragma unroll 8
    for (int i = 0; i < 64; ++i) {
      float4 a = dv[i], c = wv[i];
      s += a.x * c.x + a.y * c.y + a.z * c.z + a.w * c.w;
    }
    part[t] = s;
    __syncthreads();
    if (seg == 0) {
      float l = part[t] + part[t + 1] + part[t + 2] + part[t + 3] + rb[e];
      lg64[p] = l;
      out_logits[p] = l;
    }
    __syncthreads();
    if (t < 8) {
      float l[8];
      float mx = -1e30f;
#pragma unroll
      for (int k = 0; k < 8; ++k) { l[k] = lg64[t * 8 + k]; mx = fmaxf(mx, l[k]); }
      float pe[8];
      float sum = 0.f;
#pragma unroll
      for (int k = 0; k < 8; ++k) { pe[k] = expf(l[k] - mx); sum += pe[k]; }
      float inv = 1.f / sum;
#pragma unroll
      for (int k = 0; k < 8; ++k) { pe[k] *= inv; probs[t * 8 + k] = pe[k]; }
      int i0 = 0;
#pragma unroll
      for (int k = 1; k < 8; ++k) if (pe[k] > pe[i0]) i0 = k;
      int i1 = (i0 == 0) ? 1 : 0;
#pragma unroll
      for (int k = 0; k < 8; ++k) if (k != i0 && pe[k] > pe[i1]) i1 = k;
      float p0 = pe[i0], p1 = pe[i1];
      float invs = 1.f / (p0 + p1);
      idx_ws[t * 2] = i0;
      idx_ws[t * 2 + 1] = i1;
      w_ws[t * 2] = p0 * invs;
      w_ws[t * 2 + 1] = p1 * invs;
#pragma unroll
      for (int k = 0; k < 8; ++k) {
        float m = (k == i0 || k == i1) ? 1.f : 0.f;
        msk[t * 8 + k] = m;
        out_mask[t * 8 + k] = m;
      }
    }
    __syncthreads();
    if (t == 0) {
      float aux = 0.f;
#pragma unroll
      for (int k = 0; k < 8; ++k) {
        float mp = 0.f, mm = 0.f;
#pragma unroll
        for (int bb = 0; bb < 8; ++bb) { mp += probs[bb * 8 + k]; mm += msk[bb * 8 + k]; }
        aux += (mp * 0.125f) * (mm * 0.125f);
      }
      out_aux[0] = 8.f * aux;
    }
  }
}

// ---------------------------------------------------------------------------
// Double-buffered MFMA K-loop, 128x128 tile (m97 structure), 4 waves, each
// wave a 64x64 quadrant = 4x4 x mfma_f32_16x16x32_bf16 (16 MFMA/wave/K-step).
// A (128-row slice, K-major), Bt (128-col slice, K-major).
// LDS: sA = 2 x 8192 B, sB = 2 x 8192 B.  XOR-swizzled 16B chunks
// (pre-swizzled global source addr, linear glds16 dest -> swizzled read).
// Barrier-at-top + prefetch-after-barrier: the vmcnt(0) drain at the NEXT
// barrier overlaps with this iteration's MFMA+ds_read work.
// ---------------------------------------------------------------------------
__device__ __forceinline__ void kloop_128x128(const bf16_t* __restrict__ A,
                                              const bf16_t* __restrict__ Bt,
                                              char* sA, char* sB, int t,
                                              f32x4 acc[4][4]) {
  const int lane = t & 63;
  const int w = t >> 6, wr = w >> 1, wc = w & 1;
  const int m15 = lane & 15, q = lane >> 4;
  const int rl = t >> 2, cp = (t & 3) ^ (rl & 3);
  // rows 64..127 have the same (row&3) as rows 0..63 -> same swizzle chunk
  const bf16_t* ga0 = A  + (size_t)rl * DIM + cp * 8;
  const bf16_t* ga1 = ga0 + (size_t)64 * DIM;
  const bf16_t* gb0 = Bt + (size_t)rl * DIM + cp * 8;
  const bf16_t* gb1 = gb0 + (size_t)64 * DIM;

  const char* ra[4];
  const char* rb[4];
#pragma unroll
  for (int i = 0; i < 4; ++i) {
    const int r = wr * 64 + i * 16 + m15;
    ra[i] = sA + r * 64 + ((q ^ (r & 3)) * 16);
    const int n = wc * 64 + i * 16 + m15;
    rb[i] = sB + n * 64 + ((q ^ (n & 3)) * 16);
  }

  // prologue: stage k-tile 0 into buffer 0 (A rows 0-63, 64-127; same for B)
  glds16(ga0, sA + t * 16);
  glds16(ga1, sA + 4096 + t * 16);
  glds16(gb0, sB + t * 16);
  glds16(gb1, sB + 4096 + t * 16);

  for (int kt = 0; kt < 32; ++kt) {
    const int cur = kt & 1;
    __syncthreads();                    // drains stage(kt); prev reads retired
    if (kt < 31) {                      // prefetch kt+1 into other buffer
      const int nxt = cur ^ 1;
      const int off = (kt + 1) * 32;
      glds16(ga0 + off, sA + nxt * 8192 + t * 16);
      glds16(ga1 + off, sA + nxt * 8192 + 4096 + t * 16);
      glds16(gb0 + off, sB + nxt * 8192 + t * 16);
      glds16(gb1 + off, sB + nxt * 8192 + 4096 + t * 16);
    }
    bf16x8 af[4], bfr[4];
#pragma unroll
    for (int i = 0; i < 4; ++i) af[i] = *(const bf16x8*)(ra[i] + cur * 8192);
#pragma unroll
    for (int j = 0; j < 4; ++j) bfr[j] = *(const bf16x8*)(rb[j] + cur * 8192);
#pragma unroll
    for (int i = 0; i < 4; ++i)
#pragma unroll
      for (int j = 0; j < 4; ++j)
        acc[i][j] = __builtin_amdgcn_mfma_f32_16x16x32_bf16(af[i], bfr[j], acc[i][j], 0, 0, 0);
  }
}

// ---------------------------------------------------------------------------
// GEMM1: hidden[slot] = relu(x[b] @ w1[e] + b1[e]), bf16 out via LDS bounce.
// grid (8 N, 4 M, 16 slots) = 512 blocks, 256 thr, 2+ blocks/CU.
// ---------------------------------------------------------------------------
__global__ __launch_bounds__(256, 2) void gemm1_kernel(const bf16_t* __restrict__ xb,
                                                       const bf16_t* __restrict__ w1t,
                                                       const float* __restrict__ b1,
                                                       const int* __restrict__ topk_idx,
                                                       bf16_t* __restrict__ hidden) {
  __shared__ __align__(16) char smem[34816];   // max(staging 32768, bounce 34816)
  const int tid = threadIdx.x;
  const int bN = blockIdx.x, bM = blockIdx.y, slot = blockIdx.z;
  const int b = slot >> 1;
  const int e = topk_idx[slot];

  const bf16_t* A  = xb + ((size_t)b * SEQL + bM * 128) * DIM;
  const bf16_t* Bt = w1t + ((size_t)e * DIM + bN * 128) * DIM;

  f32x4 acc[4][4];
#pragma unroll
  for (int i = 0; i < 4; ++i)
#pragma unroll
    for (int j = 0; j < 4; ++j) acc[i][j] = {0.f, 0.f, 0.f, 0.f};

  kloop_128x128(A, Bt, smem, smem + 16384, tid, acc);

  // epilogue: bias + relu + cast, bounce through LDS for 16B stores.
  // C/D layout: col = lane&15, row = quad*4 + reg (m89-verified).
  __syncthreads();                       // staging reads done; reuse smem
  bf16_t* hb = (bf16_t*)smem;            // [128][136] halfwords (272B rows, 16B-aligned)
  const int lane = tid & 63, w = tid >> 6;
  const int wr = w >> 1, wc = w & 1;
  const int m15 = lane & 15, q = lane >> 4;
  const float* be = b1 + e * DIM;
#pragma unroll
  for (int i = 0; i < 4; ++i)
#pragma unroll
    for (int j = 0; j < 4; ++j) {
      const int colL = wc * 64 + j * 16 + m15;
      const float bias = be[bN * 128 + colL];
#pragma unroll
      for (int r = 0; r < 4; ++r) {
        const int rowL = wr * 64 + i * 16 + q * 4 + r;
        hb[rowL * 136 + colL] = (bf16_t)fmaxf(acc[i][j][r] + bias, 0.f);
      }
    }
  __syncthreads();
  bf16_t* H = hidden + (size_t)slot * SEQL * DIM + ((size_t)bM * 128) * DIM + bN * 128;
#pragma unroll
  for (int ii = 0; ii < 8; ++ii) {
    const int r = (tid >> 4) + 16 * ii;
    const int c = tid & 15;
    bf16x8 vv = *(const bf16x8*)(hb + r * 136 + c * 8);
    *(bf16x8*)(H + (size_t)r * DIM + c * 8) = vv;
  }
}

// ---------------------------------------------------------------------------
// GEMM2: out[b] = w0*(h0 @ w2[e0]) + w1*(h1 @ w2[e1]) + combined bias, fp32.
// One block per 128x128 output tile runs TWO sequential kloops (expert 0
// then expert 1) into one accumulator, using acc *= (w0/w1) between them so
// the final store is w1*acc = w0*P0 + w1*P1.  No atomics, no pairing LDS.
// grid (8 N, 4 M, 8 b) = 256 blocks, 256 thr.
// ---------------------------------------------------------------------------
__global__ __launch_bounds__(256, 2) void gemm2_kernel(const bf16_t* __restrict__ hidden,
                                                       const bf16_t* __restrict__ w2t,
                                                       const float* __restrict__ b2,
                                                       const int* __restrict__ topk_idx,
                                                       const float* __restrict__ topk_w,
                                                       float* __restrict__ out) {
  __shared__ __align__(16) char smem[32768];
  const int tid = threadIdx.x;
  const int bN = blockIdx.x, bM = blockIdx.y, b = blockIdx.z;
  const int e0 = topk_idx[b * 2], e1 = topk_idx[b * 2 + 1];
  const float w0 = topk_w[b * 2], w1v = topk_w[b * 2 + 1];

  f32x4 acc[4][4];
#pragma unroll
  for (int i = 0; i < 4; ++i)
#pragma unroll
    for (int j = 0; j < 4; ++j) acc[i][j] = {0.f, 0.f, 0.f, 0.f};

  // expert slot 0
  {
    const bf16_t* A  = hidden + ((size_t)(b * 2) * SEQL + bM * 128) * DIM;
    const bf16_t* Bt = w2t + ((size_t)e0 * DIM + bN * 128) * DIM;
    kloop_128x128(A, Bt, smem, smem + 16384, tid, acc);
  }
  // acc = (w0/w1)*P0 ; softmax probs => w1v > 0 always
  const float ratio = w0 / w1v;
#pragma unroll
  for (int i = 0; i < 4; ++i)
#pragma unroll
    for (int j = 0; j < 4; ++j)
#pragma unroll
      for (int r = 0; r < 4; ++r) acc[i][j][r] *= ratio;
  // expert slot 1 accumulates raw P1 on top (buffer handoff is race-free:
  // prologue writes buf0 while any straggler reads buf1; first barrier of
  // the new kloop orders everything else)
  {
    const bf16_t* A  = hidden + ((size_t)(b * 2 + 1) * SEQL + bM * 128) * DIM;
    const bf16_t* Bt = w2t + ((size_t)e1 * DIM + bN * 128) * DIM;
    kloop_128x128(A, Bt, smem, smem + 16384, tid, acc);
  }

  // epilogue: out = w1v*acc + (w0*b2[e0] + w1v*b2[e1]), direct fp32 stores
  // (16 consecutive lanes = 64B contiguous per row -> 4 sectors/instr).
  const int lane = tid & 63, w = tid >> 6;
  const int wr = w >> 1, wc = w & 1;
  const int m15 = lane & 15, q = lane >> 4;
  const float* be0 = b2 + e0 * DIM;
  const float* be1 = b2 + e1 * DIM;
  float* O = out + (size_t)b * SEQL * DIM;
#pragma unroll
  for (int i = 0; i < 4; ++i)
#pragma unroll
    for (int j = 0; j < 4; ++j) {
      const int col = bN * 128 + wc * 64 + j * 16 + m15;
      const float bb = w0 * be0[col] + w1v * be1[col];
      const int row = bM * 128 + wr * 64 + i * 16 + q * 4;
#pragma unroll
      for (int r = 0; r < 4; ++r)
        O[(size_t)(row + r) * DIM + col] = w1v * acc[i][j][r] + bb;
    }
}

// ---------------------------------------------------------------------------
extern "C" void kernel_launch(void* const* d_in, const int* in_sizes, int n_in,
                              void* d_out, int out_size, void* d_ws, size_t ws_size,
                              hipStream_t stream) {
  const float* x   = (const float*)d_in[0];
  const float* dec = (const float*)d_in[1];
  const float* rw  = (const float*)d_in[2];
  const float* rb  = (const float*)d_in[3];
  const float* w1  = (const float*)d_in[4];
  const float* w2  = (const float*)d_in[5];
  const float* b1  = (const float*)d_in[6];
  const float* b2  = (const float*)d_in[7];
  float* out = (float*)d_out;

  // ws layout: xb 8MB | w1t 16MB | w2t 16MB | hidden 16MB | router scratch
  char* ws = (char*)d_ws;
  bf16_t* xb   = (bf16_t*)(ws);
  bf16_t* w1t  = (bf16_t*)(ws + (8u << 20));
  bf16_t* w2t  = (bf16_t*)(ws + (24u << 20));
  bf16_t* hid  = (bf16_t*)(ws + (40u << 20));
  int*    idxw = (int*)(ws + (56u << 20));
  float*  ww   = (float*)(ws + (56u << 20) + 64);

  hipLaunchKernelGGL(prep_kernel, dim3(2048 + 512 + 1), dim3(256), 0, stream,
                     x, dec, rw, rb, w1, w2, xb, w1t, w2t,
                     out + OFF_AUX, out + OFF_MASK, out + OFF_LOGITS, idxw, ww);
  hipLaunchKernelGGL(gemm1_kernel, dim3(8, 4, 16), dim3(256), 0, stream,
                     xb, w1t, b1, idxw, hid);
  hipLaunchKernelGGL(gemm2_kernel, dim3(8, 4, 8), dim3(256), 0, stream,
                     hid, w2t, b2, idxw, ww, out);
}

// Round 3
// 192.262 us; speedup vs baseline: 1.0527x; 1.0274x over previous
//
#include <hip/hip_runtime.h>
#include <hip/hip_bf16.h>
#include <stdint.h>

// Problem constants
#define EXP 8
#define DIM 1024
#define SEQL 512
#define BATCH 8
#define OUT_FINAL_N (BATCH * SEQL * DIM)   // 4194304
#define OFF_AUX    4194304
#define OFF_MASK   4194305
#define OFF_LOGITS 4194369

typedef __bf16 bf16_t;
typedef bf16_t bf16x8 __attribute__((ext_vector_type(8)));
typedef bf16_t bf16x4 __attribute__((ext_vector_type(4)));
typedef float  f32x4  __attribute__((ext_vector_type(4)));

typedef __attribute__((address_space(1))) void* as1p;
typedef __attribute__((address_space(3))) void* as3p;

__device__ __forceinline__ void glds16(const void* g, void* l) {
  // async global->LDS, 16B per lane; LDS dest = wave-uniform base + lane*16
  __builtin_amdgcn_global_load_lds((as1p)(void*)g, (as3p)l, 16, 0, 0);
}

// ---------------------------------------------------------------------------
// prep_kernel: fused { weight transpose-cast | x cast | router }.
// grid.x = 4096 (transpose 64k x 64n tiles) + 512 (x cast) + 1 (router).
// Tile shrunk 128x64 -> 64x64 (LDS 33KB -> 16.6KB) so 8 blocks/CU fit:
// prep was latency-bound (Occupancy 24%, VALUBusy 2.7%) at 4 blocks/CU.
// ---------------------------------------------------------------------------
__global__ __launch_bounds__(256) void prep_kernel(
    const float* __restrict__ x, const float* __restrict__ dec,
    const float* __restrict__ rw, const float* __restrict__ rb,
    const float* __restrict__ w1, const float* __restrict__ w2,
    bf16_t* __restrict__ xb, bf16_t* __restrict__ w1t, bf16_t* __restrict__ w2t,
    float* __restrict__ out_aux, float* __restrict__ out_mask,
    float* __restrict__ out_logits, int* __restrict__ idx_ws,
    float* __restrict__ w_ws) {
  __shared__ float tile[64][65];     // 16640 B, [n][k] transposed tile
  __shared__ float part[256];
  __shared__ float lg64[64];
  __shared__ float probs[64];
  __shared__ float msk[64];
  const int bid = blockIdx.x;
  const int t = threadIdx.x;

  if (bid < 4096) {
    // ---- transpose-cast: matrix z, tile = 64 k-rows x 64 n-cols ----
    const int z = bid >> 8;              // 16 matrices
    const int rem = bid & 255;
    const int k0 = (rem >> 4) * 64;      // 16 k-tiles
    const int n0 = (rem & 15) * 64;      // 16 n-tiles
    const float* src = (z < 8) ? (w1 + (size_t)z * DIM * DIM)
                               : (w2 + (size_t)(z - 8) * DIM * DIM);
    bf16_t* dst = (z < 8) ? (w1t + (size_t)z * DIM * DIM)
                          : (w2t + (size_t)(z - 8) * DIM * DIM);
    const int rr = t >> 4, c4 = t & 15;
    float4 v[4];
#pragma unroll
    for (int i = 0; i < 4; ++i)
      v[i] = *(const float4*)(src + (size_t)(k0 + rr + 16 * i) * DIM + n0 + c4 * 4);
#pragma unroll
    for (int i = 0; i < 4; ++i) {
      const int k = rr + 16 * i;
      tile[c4 * 4 + 0][k] = v[i].x;
      tile[c4 * 4 + 1][k] = v[i].y;
      tile[c4 * 4 + 2][k] = v[i].z;
      tile[c4 * 4 + 3][k] = v[i].w;
    }
    __syncthreads();
    // read k-contiguous, cast, 16B stores
#pragma unroll
    for (int ii = 0; ii < 2; ++ii) {
      const int n = (t >> 3) + 32 * ii;
      const int c = t & 7;
      bf16x8 o;
#pragma unroll
      for (int wd = 0; wd < 8; ++wd) o[wd] = (bf16_t)tile[n][c * 8 + wd];
      *(bf16x8*)(dst + (size_t)(n0 + n) * DIM + k0 + c * 8) = o;
    }
  } else if (bid < 4096 + 512) {
    // ---- cast x: 1M float4s over 512 blocks, 8 per thread, batched ----
    const int i0 = (bid - 4096) * 2048 + t;
    float4 v[8];
#pragma unroll
    for (int i = 0; i < 8; ++i) v[i] = ((const float4*)x)[i0 + i * 256];
#pragma unroll
    for (int i = 0; i < 8; ++i) {
      bf16x4 o;
      o[0] = (bf16_t)v[i].x; o[1] = (bf16_t)v[i].y;
      o[2] = (bf16_t)v[i].z; o[3] = (bf16_t)v[i].w;
      ((bf16x4*)xb)[i0 + i * 256] = o;
    }
  } else {
    // ---- router ----
    const int p = t >> 2, seg = t & 3;
    const int b = p >> 3, e = p & 7;
    const float4* dv = (const float4*)(dec + b * DIM + seg * 256);
    const float4* wv = (const float4*)(rw + e * DIM + seg * 256);
    float s = 0.f;
#pragma unroll 8
    for (int i = 0; i < 64; ++i) {
      float4 a = dv[i], c = wv[i];
      s += a.x * c.x + a.y * c.y + a.z * c.z + a.w * c.w;
    }
    part[t] = s;
    __syncthreads();
    if (seg == 0) {
      float l = part[t] + part[t + 1] + part[t + 2] + part[t + 3] + rb[e];
      lg64[p] = l;
      out_logits[p] = l;
    }
    __syncthreads();
    if (t < 8) {
      float l[8];
      float mx = -1e30f;
#pragma unroll
      for (int k = 0; k < 8; ++k) { l[k] = lg64[t * 8 + k]; mx = fmaxf(mx, l[k]); }
      float pe[8];
      float sum = 0.f;
#pragma unroll
      for (int k = 0; k < 8; ++k) { pe[k] = expf(l[k] - mx); sum += pe[k]; }
      float inv = 1.f / sum;
#pragma unroll
      for (int k = 0; k < 8; ++k) { pe[k] *= inv; probs[t * 8 + k] = pe[k]; }
      int i0 = 0;
#pragma unroll
      for (int k = 1; k < 8; ++k) if (pe[k] > pe[i0]) i0 = k;
      int i1 = (i0 == 0) ? 1 : 0;
#pragma unroll
      for (int k = 0; k < 8; ++k) if (k != i0 && pe[k] > pe[i1]) i1 = k;
      float p0 = pe[i0], p1 = pe[i1];
      float invs = 1.f / (p0 + p1);
      idx_ws[t * 2] = i0;
      idx_ws[t * 2 + 1] = i1;
      w_ws[t * 2] = p0 * invs;
      w_ws[t * 2 + 1] = p1 * invs;
#pragma unroll
      for (int k = 0; k < 8; ++k) {
        float m = (k == i0 || k == i1) ? 1.f : 0.f;
        msk[t * 8 + k] = m;
        out_mask[t * 8 + k] = m;
      }
    }
    __syncthreads();
    if (t == 0) {
      float aux = 0.f;
#pragma unroll
      for (int k = 0; k < 8; ++k) {
        float mp = 0.f, mm = 0.f;
#pragma unroll
        for (int bb = 0; bb < 8; ++bb) { mp += probs[bb * 8 + k]; mm += msk[bb * 8 + k]; }
        aux += (mp * 0.125f) * (mm * 0.125f);
      }
      out_aux[0] = 8.f * aux;
    }
  }
}

// ---------------------------------------------------------------------------
// Counted-vmcnt MFMA K-loop (T3/T4), 128x128 tile, 4 waves, 3 LDS buffers,
// 2-deep prefetch.  Never drains vmcnt to 0 in steady state:
//   iter kt: s_waitcnt vmcnt(4)   // stage(kt) landed; stage(kt+1) in flight
//            s_barrier            // all waves' stage(kt) landed
//            issue stage(kt+2) -> buf[(kt+2)%3]   // last read at kt-1: safe
//            ds_read buf[kt%3]; lgkm (compiler); setprio(1); 16 MFMA
// Safety: every wave's lgkm drain precedes its MFMAs, which precede the next
// barrier, so buffer (kt+2)%3 is no longer being read when its glds writes
// can land.  "memory"-clobber asm brackets the barrier so the compiler can't
// hoist ds_reads across it (other waves stage the rows this wave reads).
// LDS: sA = 3 x 8192 B, sB = 3 x 8192 B.  XOR-swizzled 16B chunks.
// ---------------------------------------------------------------------------
__device__ __forceinline__ void kloop_128x128(const bf16_t* __restrict__ A,
                                              const bf16_t* __restrict__ Bt,
                                              char* sA, char* sB, int t,
                                              f32x4 acc[4][4]) {
  const int lane = t & 63;
  const int w = t >> 6, wr = w >> 1, wc = w & 1;
  const int m15 = lane & 15, q = lane >> 4;
  const int rl = t >> 2, cp = (t & 3) ^ (rl & 3);
  const bf16_t* ga0 = A  + (size_t)rl * DIM + cp * 8;
  const bf16_t* ga1 = ga0 + (size_t)64 * DIM;
  const bf16_t* gb0 = Bt + (size_t)rl * DIM + cp * 8;
  const bf16_t* gb1 = gb0 + (size_t)64 * DIM;

  const char* ra[4];
  const char* rb[4];
#pragma unroll
  for (int i = 0; i < 4; ++i) {
    const int r = wr * 64 + i * 16 + m15;
    ra[i] = sA + r * 64 + ((q ^ (r & 3)) * 16);
    const int n = wc * 64 + i * 16 + m15;
    rb[i] = sB + n * 64 + ((q ^ (n & 3)) * 16);
  }

  // prologue: stage k-tiles 0 and 1 into buffers 0 and 1 (8 loads in flight)
  glds16(ga0, sA + t * 16);
  glds16(ga1, sA + 4096 + t * 16);
  glds16(gb0, sB + t * 16);
  glds16(gb1, sB + 4096 + t * 16);
  glds16(ga0 + 32, sA + 8192 + t * 16);
  glds16(ga1 + 32, sA + 8192 + 4096 + t * 16);
  glds16(gb0 + 32, sB + 8192 + t * 16);
  glds16(gb1 + 32, sB + 8192 + 4096 + t * 16);

  int cur = 0;                          // kt % 3
  for (int kt = 0; kt < 32; ++kt) {
    if (kt < 31) {
      asm volatile("s_waitcnt vmcnt(4)" ::: "memory");
    } else {
      asm volatile("s_waitcnt vmcnt(0)" ::: "memory");   // only stage(31) left
    }
    __builtin_amdgcn_s_barrier();
    asm volatile("" ::: "memory");      // no ds_read hoists above the barrier
    if (kt < 30) {                      // prefetch kt+2 into rotated buffer
      int nb = cur + 2; if (nb >= 3) nb -= 3;
      const int off = (kt + 2) * 32;
      char* dA = sA + nb * 8192 + t * 16;
      char* dB = sB + nb * 8192 + t * 16;
      glds16(ga0 + off, dA);
      glds16(ga1 + off, dA + 4096);
      glds16(gb0 + off, dB);
      glds16(gb1 + off, dB + 4096);
    }
    bf16x8 af[4], bfr[4];
#pragma unroll
    for (int i = 0; i < 4; ++i) af[i] = *(const bf16x8*)(ra[i] + cur * 8192);
#pragma unroll
    for (int j = 0; j < 4; ++j) bfr[j] = *(const bf16x8*)(rb[j] + cur * 8192);
    __builtin_amdgcn_s_setprio(1);
#pragma unroll
    for (int i = 0; i < 4; ++i)
#pragma unroll
      for (int j = 0; j < 4; ++j)
        acc[i][j] = __builtin_amdgcn_mfma_f32_16x16x32_bf16(af[i], bfr[j], acc[i][j], 0, 0, 0);
    __builtin_amdgcn_s_setprio(0);
    cur += 1; if (cur == 3) cur = 0;
  }
}

// ---------------------------------------------------------------------------
// GEMM1: hidden[slot] = relu(x[b] @ w1[e] + b1[e]), bf16 out via LDS bounce.
// grid (8 N, 4 M, 16 slots) = 512 blocks, 256 thr, 2 blocks/CU.
// ---------------------------------------------------------------------------
__global__ __launch_bounds__(256, 2) void gemm1_kernel(const bf16_t* __restrict__ xb,
                                                       const bf16_t* __restrict__ w1t,
                                                       const float* __restrict__ b1,
                                                       const int* __restrict__ topk_idx,
                                                       bf16_t* __restrict__ hidden) {
  __shared__ __align__(16) char smem[49152];   // staging 3x(8K+8K); bounce 34816 reuses
  const int tid = threadIdx.x;
  const int bN = blockIdx.x, bM = blockIdx.y, slot = blockIdx.z;
  const int b = slot >> 1;
  const int e = topk_idx[slot];

  const bf16_t* A  = xb + ((size_t)b * SEQL + bM * 128) * DIM;
  const bf16_t* Bt = w1t + ((size_t)e * DIM + bN * 128) * DIM;

  f32x4 acc[4][4];
#pragma unroll
  for (int i = 0; i < 4; ++i)
#pragma unroll
    for (int j = 0; j < 4; ++j) acc[i][j] = {0.f, 0.f, 0.f, 0.f};

  kloop_128x128(A, Bt, smem, smem + 24576, tid, acc);

  // epilogue: bias + relu + cast, bounce through LDS for 16B stores.
  // C/D layout: col = lane&15, row = quad*4 + reg (m89-verified).
  __syncthreads();                       // all reads retired; reuse smem
  bf16_t* hb = (bf16_t*)smem;            // [128][136] halfwords (272B rows)
  const int lane = tid & 63, w = tid >> 6;
  const int wr = w >> 1, wc = w & 1;
  const int m15 = lane & 15, q = lane >> 4;
  const float* be = b1 + e * DIM;
#pragma unroll
  for (int i = 0; i < 4; ++i)
#pragma unroll
    for (int j = 0; j < 4; ++j) {
      const int colL = wc * 64 + j * 16 + m15;
      const float bias = be[bN * 128 + colL];
#pragma unroll
      for (int r = 0; r < 4; ++r) {
        const int rowL = wr * 64 + i * 16 + q * 4 + r;
        hb[rowL * 136 + colL] = (bf16_t)fmaxf(acc[i][j][r] + bias, 0.f);
      }
    }
  __syncthreads();
  bf16_t* H = hidden + (size_t)slot * SEQL * DIM + ((size_t)bM * 128) * DIM + bN * 128;
#pragma unroll
  for (int ii = 0; ii < 8; ++ii) {
    const int r = (tid >> 4) + 16 * ii;
    const int c = tid & 15;
    bf16x8 vv = *(const bf16x8*)(hb + r * 136 + c * 8);
    *(bf16x8*)(H + (size_t)r * DIM + c * 8) = vv;
  }
}

// ---------------------------------------------------------------------------
// GEMM2: out[b] = w0*(h0 @ w2[e0]) + w1*(h1 @ w2[e1]) + combined bias, fp32.
// One block per 128x128 output tile runs TWO sequential kloops (expert 0
// then expert 1) into one accumulator via the acc *= (w0/w1) rescale.
// grid (8 N, 4 M, 8 b) = 256 blocks, 256 thr.
// ---------------------------------------------------------------------------
__global__ __launch_bounds__(256, 2) void gemm2_kernel(const bf16_t* __restrict__ hidden,
                                                       const bf16_t* __restrict__ w2t,
                                                       const float* __restrict__ b2,
                                                       const int* __restrict__ topk_idx,
                                                       const float* __restrict__ topk_w,
                                                       float* __restrict__ out) {
  __shared__ __align__(16) char smem[49152];
  const int tid = threadIdx.x;
  const int bN = blockIdx.x, bM = blockIdx.y, b = blockIdx.z;
  const int e0 = topk_idx[b * 2], e1 = topk_idx[b * 2 + 1];
  const float w0 = topk_w[b * 2], w1v = topk_w[b * 2 + 1];

  f32x4 acc[4][4];
#pragma unroll
  for (int i = 0; i < 4; ++i)
#pragma unroll
    for (int j = 0; j < 4; ++j) acc[i][j] = {0.f, 0.f, 0.f, 0.f};

  // expert slot 0
  {
    const bf16_t* A  = hidden + ((size_t)(b * 2) * SEQL + bM * 128) * DIM;
    const bf16_t* Bt = w2t + ((size_t)e0 * DIM + bN * 128) * DIM;
    kloop_128x128(A, Bt, smem, smem + 24576, tid, acc);
  }
  // acc = (w0/w1)*P0 ; softmax probs => w1v > 0 always
  const float ratio = w0 / w1v;
#pragma unroll
  for (int i = 0; i < 4; ++i)
#pragma unroll
    for (int j = 0; j < 4; ++j)
#pragma unroll
      for (int r = 0; r < 4; ++r) acc[i][j][r] *= ratio;
  // barrier before kloop 2: its prologue writes buf0/1, which stragglers of
  // kloop 1's last iterations may still be reading (real WAR race otherwise)
  __syncthreads();
  {
    const bf16_t* A  = hidden + ((size_t)(b * 2 + 1) * SEQL + bM * 128) * DIM;
    const bf16_t* Bt = w2t + ((size_t)e1 * DIM + bN * 128) * DIM;
    kloop_128x128(A, Bt, smem, smem + 24576, tid, acc);
  }

  // epilogue: out = w1v*acc + (w0*b2[e0] + w1v*b2[e1]), direct fp32 stores.
  const int lane = tid & 63, w = tid >> 6;
  const int wr = w >> 1, wc = w & 1;
  const int m15 = lane & 15, q = lane >> 4;
  const float* be0 = b2 + e0 * DIM;
  const float* be1 = b2 + e1 * DIM;
  float* O = out + (size_t)b * SEQL * DIM;
#pragma unroll
  for (int i = 0; i < 4; ++i)
#pragma unroll
    for (int j = 0; j < 4; ++j) {
      const int col = bN * 128 + wc * 64 + j * 16 + m15;
      const float bb = w0 * be0[col] + w1v * be1[col];
      const int row = bM * 128 + wr * 64 + i * 16 + q * 4;
#pragma unroll
      for (int r = 0; r < 4; ++r)
        O[(size_t)(row + r) * DIM + col] = w1v * acc[i][j][r] + bb;
    }
}

// ---------------------------------------------------------------------------
extern "C" void kernel_launch(void* const* d_in, const int* in_sizes, int n_in,
                              void* d_out, int out_size, void* d_ws, size_t ws_size,
                              hipStream_t stream) {
  const float* x   = (const float*)d_in[0];
  const float* dec = (const float*)d_in[1];
  const float* rw  = (const float*)d_in[2];
  const float* rb  = (const float*)d_in[3];
  const float* w1  = (const float*)d_in[4];
  const float* w2  = (const float*)d_in[5];
  const float* b1  = (const float*)d_in[6];
  const float* b2  = (const float*)d_in[7];
  float* out = (float*)d_out;

  // ws layout: xb 8MB | w1t 16MB | w2t 16MB | hidden 16MB | router scratch
  char* ws = (char*)d_ws;
  bf16_t* xb   = (bf16_t*)(ws);
  bf16_t* w1t  = (bf16_t*)(ws + (8u << 20));
  bf16_t* w2t  = (bf16_t*)(ws + (24u << 20));
  bf16_t* hid  = (bf16_t*)(ws + (40u << 20));
  int*    idxw = (int*)(ws + (56u << 20));
  float*  ww   = (float*)(ws + (56u << 20) + 64);

  hipLaunchKernelGGL(prep_kernel, dim3(4096 + 512 + 1), dim3(256), 0, stream,
                     x, dec, rw, rb, w1, w2, xb, w1t, w2t,
                     out + OFF_AUX, out + OFF_MASK, out + OFF_LOGITS, idxw, ww);
  hipLaunchKernelGGL(gemm1_kernel, dim3(8, 4, 16), dim3(256), 0, stream,
                     xb, w1t, b1, idxw, hid);
  hipLaunchKernelGGL(gemm2_kernel, dim3(8, 4, 8), dim3(256), 0, stream,
                     hid, w2t, b2, idxw, ww, out);
}

// Round 4
// 191.304 us; speedup vs baseline: 1.0580x; 1.0050x over previous
//
#include <hip/hip_runtime.h>
#include <hip/hip_bf16.h>
#include <stdint.h>

// Problem constants
#define EXP 8
#define DIM 1024
#define SEQL 512
#define BATCH 8
#define OUT_FINAL_N (BATCH * SEQL * DIM)   // 4194304
#define OFF_AUX    4194304
#define OFF_MASK   4194305
#define OFF_LOGITS 4194369

typedef __bf16 bf16_t;
typedef bf16_t bf16x8 __attribute__((ext_vector_type(8)));
typedef bf16_t bf16x4 __attribute__((ext_vector_type(4)));
typedef float  f32x4  __attribute__((ext_vector_type(4)));

typedef __attribute__((address_space(1))) void* as1p;
typedef __attribute__((address_space(3))) void* as3p;

__device__ __forceinline__ void glds16(const void* g, void* l) {
  // async global->LDS, 16B per lane; LDS dest = wave-uniform base + lane*16
  __builtin_amdgcn_global_load_lds((as1p)(void*)g, (as3p)l, 16, 0, 0);
}

// ---------------------------------------------------------------------------
// prep_kernel: fused { weight transpose-cast | x cast | router }.
// grid.x = 2048 (transpose 128k x 64n tiles) + 512 (x cast) + 1 (router).
// (Reverted to the R1-measured-faster 128x64 tile: 41.7 vs 43.5 us.)
// ---------------------------------------------------------------------------
__global__ __launch_bounds__(256) void prep_kernel(
    const float* __restrict__ x, const float* __restrict__ dec,
    const float* __restrict__ rw, const float* __restrict__ rb,
    const float* __restrict__ w1, const float* __restrict__ w2,
    bf16_t* __restrict__ xb, bf16_t* __restrict__ w1t, bf16_t* __restrict__ w2t,
    float* __restrict__ out_aux, float* __restrict__ out_mask,
    float* __restrict__ out_logits, int* __restrict__ idx_ws,
    float* __restrict__ w_ws) {
  __shared__ float tile[64][129];    // 33024 B, [n][k] transposed tile
  __shared__ float part[256];
  __shared__ float lg64[64];
  __shared__ float probs[64];
  __shared__ float msk[64];
  const int bid = blockIdx.x;
  const int t = threadIdx.x;

  if (bid < 2048) {
    // ---- transpose-cast: matrix z, tile = 128 k-rows x 64 n-cols ----
    const int z = bid >> 7;              // 16 matrices
    const int rem = bid & 127;
    const int k0 = (rem >> 4) * 128;     // 8 k-tiles
    const int n0 = (rem & 15) * 64;      // 16 n-tiles
    const float* src = (z < 8) ? (w1 + (size_t)z * DIM * DIM)
                               : (w2 + (size_t)(z - 8) * DIM * DIM);
    bf16_t* dst = (z < 8) ? (w1t + (size_t)z * DIM * DIM)
                          : (w2t + (size_t)(z - 8) * DIM * DIM);
    const int rr = t >> 4, c4 = t & 15;
    // batched loads: 8 float4 in flight (128 B/thread)
    float4 v[8];
#pragma unroll
    for (int i = 0; i < 8; ++i)
      v[i] = *(const float4*)(src + (size_t)(k0 + rr + 16 * i) * DIM + n0 + c4 * 4);
    // scatter transposed into LDS: tile[n][k]
#pragma unroll
    for (int i = 0; i < 8; ++i) {
      const int k = rr + 16 * i;
      tile[c4 * 4 + 0][k] = v[i].x;
      tile[c4 * 4 + 1][k] = v[i].y;
      tile[c4 * 4 + 2][k] = v[i].z;
      tile[c4 * 4 + 3][k] = v[i].w;
    }
    __syncthreads();
    // read k-contiguous, cast, 16B stores (wave covers 4 x 256B rows/instr)
#pragma unroll
    for (int ii = 0; ii < 4; ++ii) {
      const int n = (t >> 4) + 16 * ii;
      const int c = t & 15;
      bf16x8 o;
#pragma unroll
      for (int wd = 0; wd < 8; ++wd) o[wd] = (bf16_t)tile[n][c * 8 + wd];
      *(bf16x8*)(dst + (size_t)(n0 + n) * DIM + k0 + c * 8) = o;
    }
  } else if (bid < 2048 + 512) {
    // ---- cast x: 1M float4s over 512 blocks, 8 per thread, batched ----
    const int i0 = (bid - 2048) * 2048 + t;
    float4 v[8];
#pragma unroll
    for (int i = 0; i < 8; ++i) v[i] = ((const float4*)x)[i0 + i * 256];
#pragma unroll
    for (int i = 0; i < 8; ++i) {
      bf16x4 o;
      o[0] = (bf16_t)v[i].x; o[1] = (bf16_t)v[i].y;
      o[2] = (bf16_t)v[i].z; o[3] = (bf16_t)v[i].w;
      ((bf16x4*)xb)[i0 + i * 256] = o;
    }
  } else {
    // ---- router ----
    const int p = t >> 2, seg = t & 3;
    const int b = p >> 3, e = p & 7;
    const float4* dv = (const float4*)(dec + b * DIM + seg * 256);
    const float4* wv = (const float4*)(rw + e * DIM + seg * 256);
    float s = 0.f;
#pragma unroll 8
    for (int i = 0; i < 64; ++i) {
      float4 a = dv[i], c = wv[i];
      s += a.x * c.x + a.y * c.y + a.z * c.z + a.w * c.w;
    }
    part[t] = s;
    __syncthreads();
    if (seg == 0) {
      float l = part[t] + part[t + 1] + part[t + 2] + part[t + 3] + rb[e];
      lg64[p] = l;
      out_logits[p] = l;
    }
    __syncthreads();
    if (t < 8) {
      float l[8];
      float mx = -1e30f;
#pragma unroll
      for (int k = 0; k < 8; ++k) { l[k] = lg64[t * 8 + k]; mx = fmaxf(mx, l[k]); }
      float pe[8];
      float sum = 0.f;
#pragma unroll
      for (int k = 0; k < 8; ++k) { pe[k] = expf(l[k] - mx); sum += pe[k]; }
      float inv = 1.f / sum;
#pragma unroll
      for (int k = 0; k < 8; ++k) { pe[k] *= inv; probs[t * 8 + k] = pe[k]; }
      int i0 = 0;
#pragma unroll
      for (int k = 1; k < 8; ++k) if (pe[k] > pe[i0]) i0 = k;
      int i1 = (i0 == 0) ? 1 : 0;
#pragma unroll
      for (int k = 0; k < 8; ++k) if (k != i0 && pe[k] > pe[i1]) i1 = k;
      float p0 = pe[i0], p1 = pe[i1];
      float invs = 1.f / (p0 + p1);
      idx_ws[t * 2] = i0;
      idx_ws[t * 2 + 1] = i1;
      w_ws[t * 2] = p0 * invs;
      w_ws[t * 2 + 1] = p1 * invs;
#pragma unroll
      for (int k = 0; k < 8; ++k) {
        float m = (k == i0 || k == i1) ? 1.f : 0.f;
        msk[t * 8 + k] = m;
        out_mask[t * 8 + k] = m;
      }
    }
    __syncthreads();
    if (t == 0) {
      float aux = 0.f;
#pragma unroll
      for (int k = 0; k < 8; ++k) {
        float mp = 0.f, mm = 0.f;
#pragma unroll
        for (int bb = 0; bb < 8; ++bb) { mp += probs[bb * 8 + k]; mm += msk[bb * 8 + k]; }
        aux += (mp * 0.125f) * (mm * 0.125f);
      }
      out_aux[0] = 8.f * aux;
    }
  }
}

// ---------------------------------------------------------------------------
// GEMM1: 512-thr, 8-wave, TWO-GROUP blocks.  Group g computes slot 2b+g's
// 128x128 tile; A = x[b] is SHARED (staged once by all 512 threads), each
// group stages its own B.  Per k-step: 8KB A + 2x8KB B staged for 128
// wave-MFMAs (vs 16KB/64 in the 4-wave version) and 8 waves/CU to overlap
// the counted-vmcnt waits.  3-buffer rotation, vmcnt(3) steady state
// (3 glds16/thread/k-tile; prologue 6).  Grid (8 N, 4 M, 8 b) = 256 = 1/CU.
// ---------------------------------------------------------------------------
__global__ __launch_bounds__(512, 2) void gemm1_kernel(const bf16_t* __restrict__ xb,
                                                       const bf16_t* __restrict__ w1t,
                                                       const float* __restrict__ b1,
                                                       const int* __restrict__ topk_idx,
                                                       bf16_t* __restrict__ hidden) {
  __shared__ __align__(16) char smem[73728];   // sA 3x8K | sB0 3x8K | sB1 3x8K
  const int tid = threadIdx.x;
  const int g = tid >> 8;        // expert-slot group
  const int t = tid & 255;       // group-local index
  const int bN = blockIdx.x, bM = blockIdx.y, b = blockIdx.z;
  const int slot = b * 2 + g;
  const int e = topk_idx[slot];

  const bf16_t* A  = xb + ((size_t)b * SEQL + bM * 128) * DIM;
  const bf16_t* Bt = w1t + ((size_t)e * DIM + bN * 128) * DIM;

  char* sA = smem;                        // shared A, 3 buffers
  char* sB = smem + 24576 + g * 24576;    // per-group B, 3 buffers

  // staging addresses (XOR-swizzled global source -> linear LDS dest)
  const int rlA = tid >> 2, cpA = (tid & 3) ^ (rlA & 3);   // rows 0..127
  const bf16_t* gA = A + (size_t)rlA * DIM + cpA * 8;
  const int rlB = t >> 2, cpB = (t & 3) ^ (rlB & 3);       // rows 0..63
  const bf16_t* gB0 = Bt + (size_t)rlB * DIM + cpB * 8;
  const bf16_t* gB1 = gB0 + (size_t)64 * DIM;

  // fragment read pointers (group-local wave geometry)
  const int lane = tid & 63, wg = (tid >> 6) & 3;
  const int wr = wg >> 1, wc = wg & 1;
  const int m15 = lane & 15, q = lane >> 4;
  const char* ra[4];
  const char* rb[4];
#pragma unroll
  for (int i = 0; i < 4; ++i) {
    const int r = wr * 64 + i * 16 + m15;
    ra[i] = sA + r * 64 + ((q ^ (r & 3)) * 16);
    const int n = wc * 64 + i * 16 + m15;
    rb[i] = sB + n * 64 + ((q ^ (n & 3)) * 16);
  }

  f32x4 acc[4][4];
#pragma unroll
  for (int i = 0; i < 4; ++i)
#pragma unroll
    for (int j = 0; j < 4; ++j) acc[i][j] = {0.f, 0.f, 0.f, 0.f};

  // prologue: stage k-tiles 0 and 1 into buffers 0 and 1 (6 loads/wave)
  glds16(gA, sA + tid * 16);
  glds16(gB0, sB + t * 16);
  glds16(gB1, sB + 4096 + t * 16);
  glds16(gA + 32, sA + 8192 + tid * 16);
  glds16(gB0 + 32, sB + 8192 + t * 16);
  glds16(gB1 + 32, sB + 8192 + 4096 + t * 16);

  int cur = 0;                          // kt % 3
  for (int kt = 0; kt < 32; ++kt) {
    if (kt < 31) {
      asm volatile("s_waitcnt vmcnt(3)" ::: "memory");   // stage(kt) landed
    } else {
      asm volatile("s_waitcnt vmcnt(0)" ::: "memory");
    }
    __builtin_amdgcn_s_barrier();
    asm volatile("" ::: "memory");
    if (kt < 30) {                      // prefetch kt+2 into rotated buffer
      int nb = cur + 2; if (nb >= 3) nb -= 3;
      const int off = (kt + 2) * 32;
      glds16(gA + off, sA + nb * 8192 + tid * 16);
      glds16(gB0 + off, sB + nb * 8192 + t * 16);
      glds16(gB1 + off, sB + nb * 8192 + 4096 + t * 16);
    }
    bf16x8 af[4], bfr[4];
#pragma unroll
    for (int i = 0; i < 4; ++i) af[i] = *(const bf16x8*)(ra[i] + cur * 8192);
#pragma unroll
    for (int j = 0; j < 4; ++j) bfr[j] = *(const bf16x8*)(rb[j] + cur * 8192);
    __builtin_amdgcn_s_setprio(1);
#pragma unroll
    for (int i = 0; i < 4; ++i)
#pragma unroll
      for (int j = 0; j < 4; ++j)
        acc[i][j] = __builtin_amdgcn_mfma_f32_16x16x32_bf16(af[i], bfr[j], acc[i][j], 0, 0, 0);
    __builtin_amdgcn_s_setprio(0);
    cur += 1; if (cur == 3) cur = 0;
  }

  // epilogue: bias + relu + cast, bounce through per-group LDS region.
  // C/D layout: col = lane&15, row = quad*4 + reg (m89-verified).
  __syncthreads();                       // all reads retired; reuse smem
  bf16_t* hb = (bf16_t*)(smem + g * 34816);   // [128][136] halfwords each
  const float* be = b1 + e * DIM;
#pragma unroll
  for (int i = 0; i < 4; ++i)
#pragma unroll
    for (int j = 0; j < 4; ++j) {
      const int colL = wc * 64 + j * 16 + m15;
      const float bias = be[bN * 128 + colL];
#pragma unroll
      for (int r = 0; r < 4; ++r) {
        const int rowL = wr * 64 + i * 16 + q * 4 + r;
        hb[rowL * 136 + colL] = (bf16_t)fmaxf(acc[i][j][r] + bias, 0.f);
      }
    }
  __syncthreads();
  bf16_t* H = hidden + (size_t)slot * SEQL * DIM + ((size_t)bM * 128) * DIM + bN * 128;
#pragma unroll
  for (int ii = 0; ii < 8; ++ii) {
    const int r = (t >> 4) + 16 * ii;
    const int c = t & 15;
    bf16x8 vv = *(const bf16x8*)(hb + r * 136 + c * 8);
    *(bf16x8*)(H + (size_t)r * DIM + c * 8) = vv;
  }
}

// ---------------------------------------------------------------------------
// GEMM2: 512-thr, 8-wave, TWO-GROUP blocks.  Group g computes the scaled
// partial for slot 2b+g (own A = hidden[slot], own B = w2t[e_g]); combine
// in-block via 16KB LDS scratch in 4 chunks.  4 glds16/thread/k-tile ->
// steady vmcnt(4), prologue 8 (same counts as the R3-verified loop).
// Grid (8 N, 4 M, 8 b) = 256 blocks = 1/CU, 8 waves/CU.  LDS 96 KB.
// ---------------------------------------------------------------------------
__global__ __launch_bounds__(512, 2) void gemm2_kernel(const bf16_t* __restrict__ hidden,
                                                       const bf16_t* __restrict__ w2t,
                                                       const float* __restrict__ b2,
                                                       const int* __restrict__ topk_idx,
                                                       const float* __restrict__ topk_w,
                                                       float* __restrict__ out) {
  __shared__ __align__(16) char smem[98304];   // per group: sA 3x8K | sB 3x8K
  const int tid = threadIdx.x;
  const int g = tid >> 8;
  const int t = tid & 255;
  const int bN = blockIdx.x, bM = blockIdx.y, b = blockIdx.z;
  const int slot = b * 2 + g;
  const int e = topk_idx[slot];
  const float sg = topk_w[slot];

  const bf16_t* A  = hidden + ((size_t)slot * SEQL + bM * 128) * DIM;
  const bf16_t* Bt = w2t + ((size_t)e * DIM + bN * 128) * DIM;

  char* sA = smem + g * 49152;
  char* sB = sA + 24576;

  const int rl = t >> 2, cp = (t & 3) ^ (rl & 3);          // rows 0..63
  const bf16_t* gA0 = A + (size_t)rl * DIM + cp * 8;
  const bf16_t* gA1 = gA0 + (size_t)64 * DIM;
  const bf16_t* gB0 = Bt + (size_t)rl * DIM + cp * 8;
  const bf16_t* gB1 = gB0 + (size_t)64 * DIM;

  const int lane = tid & 63, wg = (tid >> 6) & 3;
  const int wr = wg >> 1, wc = wg & 1;
  const int m15 = lane & 15, q = lane >> 4;
  const char* ra[4];
  const char* rb[4];
#pragma unroll
  for (int i = 0; i < 4; ++i) {
    const int r = wr * 64 + i * 16 + m15;
    ra[i] = sA + r * 64 + ((q ^ (r & 3)) * 16);
    const int n = wc * 64 + i * 16 + m15;
    rb[i] = sB + n * 64 + ((q ^ (n & 3)) * 16);
  }

  f32x4 acc[4][4];
#pragma unroll
  for (int i = 0; i < 4; ++i)
#pragma unroll
    for (int j = 0; j < 4; ++j) acc[i][j] = {0.f, 0.f, 0.f, 0.f};

  // prologue: k-tiles 0 and 1 (8 loads/wave in flight)
  glds16(gA0, sA + t * 16);
  glds16(gA1, sA + 4096 + t * 16);
  glds16(gB0, sB + t * 16);
  glds16(gB1, sB + 4096 + t * 16);
  glds16(gA0 + 32, sA + 8192 + t * 16);
  glds16(gA1 + 32, sA + 8192 + 4096 + t * 16);
  glds16(gB0 + 32, sB + 8192 + t * 16);
  glds16(gB1 + 32, sB + 8192 + 4096 + t * 16);

  int cur = 0;
  for (int kt = 0; kt < 32; ++kt) {
    if (kt < 31) {
      asm volatile("s_waitcnt vmcnt(4)" ::: "memory");
    } else {
      asm volatile("s_waitcnt vmcnt(0)" ::: "memory");
    }
    __builtin_amdgcn_s_barrier();
    asm volatile("" ::: "memory");
    if (kt < 30) {
      int nb = cur + 2; if (nb >= 3) nb -= 3;
      const int off = (kt + 2) * 32;
      char* dA = sA + nb * 8192 + t * 16;
      char* dB = sB + nb * 8192 + t * 16;
      glds16(gA0 + off, dA);
      glds16(gA1 + off, dA + 4096);
      glds16(gB0 + off, dB);
      glds16(gB1 + off, dB + 4096);
    }
    bf16x8 af[4], bfr[4];
#pragma unroll
    for (int i = 0; i < 4; ++i) af[i] = *(const bf16x8*)(ra[i] + cur * 8192);
#pragma unroll
    for (int j = 0; j < 4; ++j) bfr[j] = *(const bf16x8*)(rb[j] + cur * 8192);
    __builtin_amdgcn_s_setprio(1);
#pragma unroll
    for (int i = 0; i < 4; ++i)
#pragma unroll
      for (int j = 0; j < 4; ++j)
        acc[i][j] = __builtin_amdgcn_mfma_f32_16x16x32_bf16(af[i], bfr[j], acc[i][j], 0, 0, 0);
    __builtin_amdgcn_s_setprio(0);
    cur += 1; if (cur == 3) cur = 0;
  }

  // ---- combine: group1 -> LDS scratch (16KB chunks) -> group0 adds ----
  __syncthreads();               // all staging reads done; smem reusable
  float* scr = (float*)smem;     // [16][256] fp32 per chunk, stride-1 in t
  const float w0 = topk_w[b * 2], w1v = topk_w[b * 2 + 1];
  const float* be0 = b2 + topk_idx[b * 2] * DIM;
  const float* be1 = b2 + topk_idx[b * 2 + 1] * DIM;
  float* O = out + (size_t)b * SEQL * DIM;
#pragma unroll
  for (int i = 0; i < 4; ++i) {
    if (g == 1) {
#pragma unroll
      for (int j = 0; j < 4; ++j)
#pragma unroll
        for (int r = 0; r < 4; ++r)
          scr[(j * 4 + r) * 256 + t] = sg * acc[i][j][r];
    }
    __syncthreads();
    if (g == 0) {
#pragma unroll
      for (int j = 0; j < 4; ++j) {
        const int col = bN * 128 + wc * 64 + j * 16 + m15;
        const float bb = w0 * be0[col] + w1v * be1[col];
        const int row = bM * 128 + wr * 64 + i * 16 + q * 4;
#pragma unroll
        for (int r = 0; r < 4; ++r)
          O[(size_t)(row + r) * DIM + col] =
              sg * acc[i][j][r] + scr[(j * 4 + r) * 256 + t] + bb;
      }
    }
    __syncthreads();
  }
}

// ---------------------------------------------------------------------------
extern "C" void kernel_launch(void* const* d_in, const int* in_sizes, int n_in,
                              void* d_out, int out_size, void* d_ws, size_t ws_size,
                              hipStream_t stream) {
  const float* x   = (const float*)d_in[0];
  const float* dec = (const float*)d_in[1];
  const float* rw  = (const float*)d_in[2];
  const float* rb  = (const float*)d_in[3];
  const float* w1  = (const float*)d_in[4];
  const float* w2  = (const float*)d_in[5];
  const float* b1  = (const float*)d_in[6];
  const float* b2  = (const float*)d_in[7];
  float* out = (float*)d_out;

  // ws layout: xb 8MB | w1t 16MB | w2t 16MB | hidden 16MB | router scratch
  char* ws = (char*)d_ws;
  bf16_t* xb   = (bf16_t*)(ws);
  bf16_t* w1t  = (bf16_t*)(ws + (8u << 20));
  bf16_t* w2t  = (bf16_t*)(ws + (24u << 20));
  bf16_t* hid  = (bf16_t*)(ws + (40u << 20));
  int*    idxw = (int*)(ws + (56u << 20));
  float*  ww   = (float*)(ws + (56u << 20) + 64);

  hipLaunchKernelGGL(prep_kernel, dim3(2048 + 512 + 1), dim3(256), 0, stream,
                     x, dec, rw, rb, w1, w2, xb, w1t, w2t,
                     out + OFF_AUX, out + OFF_MASK, out + OFF_LOGITS, idxw, ww);
  hipLaunchKernelGGL(gemm1_kernel, dim3(8, 4, 8), dim3(512), 0, stream,
                     xb, w1t, b1, idxw, hid);
  hipLaunchKernelGGL(gemm2_kernel, dim3(8, 4, 8), dim3(512), 0, stream,
                     hid, w2t, b2, idxw, ww, out);
}